// Round 4
// baseline (505.995 us; speedup 1.0000x reference)
//
#include <hip/hip_runtime.h>
#include <hip/hip_cooperative_groups.h>
#include <cstdint>

namespace cg = cooperative_groups;

#define B_SZ 2048
#define T_SZ 512
#define F_SZ 64
#define NG   12   // 4*H, H=3

#define TCH   128              // t-steps per pipeline chunk
#define NCH   4                // chunks (TCH*NCH == T_SZ)
#define SCANB 64               // scan blocks (64*128 = 8192 = B*4 lanes)
#define PRODB 512              // producer blocks in steady state
#define GBLK  (SCANB + PRODB)  // total grid
#define STRF  (B_SZ * NG)      // floats per t-row of xw

// log2(e); gates pre-scaled by -L2E (sigmoid) / -2*L2E (tanh) in phase 1
#define L2E 1.4426950408889634f

__device__ __forceinline__ float fast_rcp(float x) { return __builtin_amdgcn_rcpf(x); }
__device__ __forceinline__ float exp2h(float x)    { return __builtin_amdgcn_exp2f(x); }
__device__ __forceinline__ float sigm_s(float zs)  { return fast_rcp(1.0f + exp2h(zs)); }
__device__ __forceinline__ float tanh_s(float zs)  { return fmaf(2.0f, fast_rcp(1.0f + exp2h(zs)), -1.0f); }
__device__ __forceinline__ float sigm_n(float x)   { return sigm_s(x * (-L2E)); }
__device__ __forceinline__ float tanh_n(float x)   { return tanh_s(x * (-2.0f * L2E)); }

template<int CTRL>
__device__ __forceinline__ float qperm(float v) {
    return __int_as_float(__builtin_amdgcn_mov_dpp(__float_as_int(v), CTRL, 0xF, 0xF, false));
}
#define QPA 9    // lane k <- src[{1,2,0,0}[k]]  -> h_{(m+1)%3}
#define QPB 82   // lane k <- src[{2,0,1,1}[k]]  -> h_{(m+2)%3}

// ---------------- producer: one 16b x 8t tile per pass, LDS-staged ----------------
__device__ __forceinline__ void produce_chunk(const float* __restrict__ x,
                                              float* __restrict__ xw,
                                              const float* __restrict__ Ws,
                                              const float* __restrict__ bs,
                                              float* __restrict__ xs,
                                              float* __restrict__ trs,
                                              int t0, int tile0, int tstride, int tid) {
    for (int tile = tile0; tile < 2048; tile += tstride) {
        const int ttile = tile >> 7;       // 0..15 (t-tile within chunk)
        const int btile = tile & 127;      // 0..127 (b-tile)
        const int tbase = t0 + ttile * 8;

        __syncthreads();   // xs/trs of previous tile fully consumed
        // stage 16b x 8t x 64f = 32 KB, fully coalesced (2 KB runs)
        const float* src = x + ((size_t)(btile * 16) * T_SZ + tbase) * F_SZ + tid * 4;
        #pragma unroll
        for (int it = 0; it < 16; ++it) {
            const float4 v = *reinterpret_cast<const float4*>(src + (size_t)it * T_SZ * F_SZ);
            *reinterpret_cast<float4*>(xs + ((it * 8 + (tid >> 4)) * 68 + (tid & 15) * 4)) = v;
        }
        __syncthreads();

        // compute: one (b,t) row per thread
        const int bb = tid >> 3, tt = tid & 7;
        float acc[NG];
        #pragma unroll
        for (int p = 0; p < NG; ++p) acc[p] = bs[p];
        const float* row = xs + (bb * 8 + tt) * 68;
        #pragma unroll
        for (int j = 0; j < 16; ++j) {
            const float4 xv = *reinterpret_cast<const float4*>(row + 4 * j);
            #pragma unroll
            for (int jj = 0; jj < 4; ++jj) {
                const float xsv = (jj == 0) ? xv.x : (jj == 1) ? xv.y : (jj == 2) ? xv.z : xv.w;
                const float* wr = Ws + (j * 4 + jj) * NG;
                #pragma unroll
                for (int p = 0; p < NG; ++p) acc[p] = fmaf(xsv, wr[p], acc[p]);
            }
        }

        // transpose via LDS, then coalesced write of 8 t-rows x 192 floats
        float* tw = trs + tt * 196 + bb * NG;
        *reinterpret_cast<float4*>(tw + 0) = make_float4(acc[0], acc[1], acc[2],  acc[3]);
        *reinterpret_cast<float4*>(tw + 4) = make_float4(acc[4], acc[5], acc[6],  acc[7]);
        *reinterpret_cast<float4*>(tw + 8) = make_float4(acc[8], acc[9], acc[10], acc[11]);
        __syncthreads();
        const int r = tid >> 4, part = tid & 15;
        const float* lp = trs + r * 196 + part * NG;
        float* op = xw + ((size_t)(tbase + r) * B_SZ + btile * 16 + part) * NG;
        *reinterpret_cast<float4*>(op + 0) = *reinterpret_cast<const float4*>(lp + 0);
        *reinterpret_cast<float4*>(op + 4) = *reinterpret_cast<const float4*>(lp + 4);
        *reinterpret_cast<float4*>(op + 8) = *reinterpret_cast<const float4*>(lp + 8);
    }
}

// ---------------- fused cooperative kernel ----------------
__global__ __launch_bounds__(128) void fused_lstm(const float* __restrict__ x,
                                                  const float* __restrict__ W,
                                                  const float* __restrict__ U,
                                                  const float* __restrict__ bias,
                                                  const float* __restrict__ Wd,
                                                  const float* __restrict__ bdp,
                                                  float* __restrict__ out,
                                                  float* __restrict__ xw) {
    __shared__ float Ws[F_SZ * NG];
    __shared__ float bs[NG];
    __shared__ float xs[16 * 8 * 68];
    __shared__ float trs[8 * 196];

    const int tid = threadIdx.x;
    const int bid = blockIdx.x;

    // stage scaled/reordered weights (p = m*4+q  <-  W col q*3+m)
    for (int i = tid; i < F_SZ * NG; i += 128) {
        const int f = i / NG, p = i - f * NG;
        const int mm = p >> 2, q = p & 3;
        const float sc = (q == 2) ? (-2.0f * L2E) : (-L2E);
        Ws[i] = W[f * NG + q * 3 + mm] * sc;
    }
    if (tid < NG) {
        const int mm = tid >> 2, q = tid & 3;
        const float sc = (q == 2) ? (-2.0f * L2E) : (-L2E);
        bs[tid] = bias[q * 3 + mm] * sc;
    }
    __syncthreads();

    // scan-role constants (valid when bid < SCANB; harmless otherwise)
    const int g  = bid * 128 + tid;
    const int kq = g & 3;
    const int m  = (kq < 3) ? kq : 2;
    const int mn = (m + 1 == 3) ? 0 : m + 1;
    const int mp = (m + 2 >= 3) ? m - 1 : m + 2;
    float u_own[4], u_nxt[4], u_prv[4];
    #pragma unroll
    for (int q = 0; q < 4; ++q) {
        const float sc = (q == 2) ? (-2.0f * L2E) : (-L2E);
        const int col = q * 3 + m;
        u_own[q] = U[m  * NG + col] * sc;
        u_nxt[q] = U[mn * NG + col] * sc;
        u_prv[q] = U[mp * NG + col] * sc;
    }
    float h = 0.0f, c = 0.0f, hA = 0.0f, hB = 0.0f;
    const float* sbase = xw + (size_t)(g >> 2) * NG + m * 4;

    cg::grid_group gg = cg::this_grid();

    // prologue: everyone produces chunk 0
    produce_chunk(x, xw, Ws, bs, xs, trs, 0, bid, GBLK, tid);
    gg.sync();

    for (int k = 0; k < NCH; ++k) {
        if (bid < SCANB) {
            // ---- scan chunk k (xw chunk k is ready) ----
            const float* basek = sbase + (size_t)k * TCH * STRF;
            float4 pf[8];
            #pragma unroll
            for (int s = 0; s < 8; ++s)
                pf[s] = *reinterpret_cast<const float4*>(basek + (size_t)s * STRF);
            const float* pn = basek + (size_t)8 * STRF;
            for (int t = 0; t < TCH; t += 8) {
                #pragma unroll
                for (int s = 0; s < 8; ++s) {
                    const float4 z4 = pf[s];
                    if (t + 8 + s < TCH) pf[s] = *reinterpret_cast<const float4*>(pn);
                    pn += STRF;
                    const float w0 = fmaf(hA, u_nxt[0], hB * u_prv[0]);
                    const float w1 = fmaf(hA, u_nxt[1], hB * u_prv[1]);
                    const float w2 = fmaf(hA, u_nxt[2], hB * u_prv[2]);
                    const float w3 = fmaf(hA, u_nxt[3], hB * u_prv[3]);
                    const float z0 = fmaf(h, u_own[0], z4.x) + w0;
                    const float z1 = fmaf(h, u_own[1], z4.y) + w1;
                    const float z2 = fmaf(h, u_own[2], z4.z) + w2;
                    const float z3 = fmaf(h, u_own[3], z4.w) + w3;
                    const float ai = sigm_s(z0);
                    const float af = sigm_s(z1);
                    const float ag = tanh_s(z2);
                    const float ao = sigm_s(z3);
                    c = fmaf(af, c, ai * ag);
                    h = ao * tanh_n(c);
                    hA = qperm<QPA>(h);
                    hB = qperm<QPB>(h);
                }
            }
        } else if (k + 1 < NCH) {
            produce_chunk(x, xw, Ws, bs, xs, trs, (k + 1) * TCH, bid - SCANB, PRODB, tid);
        }
        if (k + 1 < NCH) gg.sync();
    }

    if (bid < SCANB) {
        const float logit = bdp[0] + h * Wd[m] + hA * Wd[mn] + hB * Wd[mp];
        if (kq == 0) out[g >> 2] = sigm_n(logit);
    }
}

// =================== fallback path (round-2, known-good) ===================
__global__ __launch_bounds__(256) void xw_phase(const float* __restrict__ x,
                                                const float* __restrict__ W,
                                                const float* __restrict__ bias,
                                                float* __restrict__ xw,
                                                int t0) {
    __shared__ float Ws[F_SZ * NG];
    __shared__ float bs[NG];
    __shared__ float trs[16][196];

    const int tid = threadIdx.x;
    for (int i = tid; i < F_SZ * NG; i += 256) {
        const int f = i / NG, p = i - f * NG;
        const int m = p >> 2, q = p & 3;
        const float sc = (q == 2) ? (-2.0f * L2E) : (-L2E);
        Ws[i] = W[f * NG + q * 3 + m] * sc;
    }
    if (tid < NG) {
        const int m = tid >> 2, q = tid & 3;
        const float sc = (q == 2) ? (-2.0f * L2E) : (-L2E);
        bs[tid] = bias[q * 3 + m] * sc;
    }
    __syncthreads();

    const int tileT = blockIdx.x;
    const int tileB = blockIdx.y;
    const int tt = tid & 15, bb = tid >> 4;
    const int t = t0 + tileT * 16 + tt;
    const int b = tileB * 16 + bb;

    const float* xp = x + ((size_t)b * T_SZ + t) * F_SZ;
    float acc[NG];
    #pragma unroll
    for (int p = 0; p < NG; ++p) acc[p] = bs[p];

    #pragma unroll
    for (int f0 = 0; f0 < F_SZ; f0 += 4) {
        const float4 xv = *reinterpret_cast<const float4*>(xp + f0);
        #pragma unroll
        for (int j = 0; j < 4; ++j) {
            const float xsv = (j == 0) ? xv.x : (j == 1) ? xv.y : (j == 2) ? xv.z : xv.w;
            const float* wr = &Ws[(f0 + j) * NG];
            #pragma unroll
            for (int p = 0; p < NG; ++p) acc[p] = fmaf(xsv, wr[p], acc[p]);
        }
    }

    float* ld = &trs[tt][bb * NG];
    *reinterpret_cast<float4*>(ld + 0) = make_float4(acc[0], acc[1], acc[2],  acc[3]);
    *reinterpret_cast<float4*>(ld + 4) = make_float4(acc[4], acc[5], acc[6],  acc[7]);
    *reinterpret_cast<float4*>(ld + 8) = make_float4(acc[8], acc[9], acc[10], acc[11]);
    __syncthreads();

    const int r = tid >> 4, off = (tid & 15) * NG;
    const float* lp = &trs[r][off];
    float* op = xw + ((size_t)(tileT * 16 + r) * B_SZ + tileB * 16) * NG + off;
    *reinterpret_cast<float4*>(op + 0) = *reinterpret_cast<const float4*>(lp + 0);
    *reinterpret_cast<float4*>(op + 4) = *reinterpret_cast<const float4*>(lp + 4);
    *reinterpret_cast<float4*>(op + 8) = *reinterpret_cast<const float4*>(lp + 8);
}

__global__ __launch_bounds__(64) void lstm_scan(const float* __restrict__ xw,
                                                const float* __restrict__ U,
                                                const float* __restrict__ Wd,
                                                const float* __restrict__ bdp,
                                                float* __restrict__ out,
                                                float* __restrict__ hbuf,
                                                float* __restrict__ cbuf,
                                                int len, int is_first, int is_last) {
    const int g = blockIdx.x * 64 + threadIdx.x;
    const int k = g & 3;
    const int m  = (k < 3) ? k : 2;
    const int mn = (m + 1 == 3) ? 0 : m + 1;
    const int mp = (m + 2 >= 3) ? m - 1 : m + 2;

    float u_own[4], u_nxt[4], u_prv[4];
    #pragma unroll
    for (int q = 0; q < 4; ++q) {
        const float sc = (q == 2) ? (-2.0f * L2E) : (-L2E);
        const int col = q * 3 + m;
        u_own[q] = U[m  * NG + col] * sc;
        u_nxt[q] = U[mn * NG + col] * sc;
        u_prv[q] = U[mp * NG + col] * sc;
    }

    float h, c, hA, hB;
    if (is_first) {
        h = c = hA = hB = 0.0f;
    } else {
        h = hbuf[g]; c = cbuf[g];
        hA = qperm<QPA>(h); hB = qperm<QPB>(h);
    }

    const size_t stride = (size_t)B_SZ * NG;
    const float* base = xw + (size_t)(g >> 2) * NG + m * 4;

    float4 pf[8];
    #pragma unroll
    for (int s = 0; s < 8; ++s)
        pf[s] = *reinterpret_cast<const float4*>(base + (size_t)s * stride);
    const float* pnext = base + 8 * stride;

    for (int t = 0; t < len; t += 8) {
        #pragma unroll
        for (int s = 0; s < 8; ++s) {
            const float4 z4 = pf[s];
            if (t + 8 + s < len) pf[s] = *reinterpret_cast<const float4*>(pnext);
            pnext += stride;
            const float z0 = fmaf(hB, u_prv[0], fmaf(hA, u_nxt[0], fmaf(h, u_own[0], z4.x)));
            const float z1 = fmaf(hB, u_prv[1], fmaf(hA, u_nxt[1], fmaf(h, u_own[1], z4.y)));
            const float z2 = fmaf(hB, u_prv[2], fmaf(hA, u_nxt[2], fmaf(h, u_own[2], z4.z)));
            const float z3 = fmaf(hB, u_prv[3], fmaf(hA, u_nxt[3], fmaf(h, u_own[3], z4.w)));
            const float ai = sigm_s(z0);
            const float af = sigm_s(z1);
            const float ag = tanh_s(z2);
            const float ao = sigm_s(z3);
            c = fmaf(af, c, ai * ag);
            h = ao * tanh_n(c);
            hA = qperm<QPA>(h);
            hB = qperm<QPB>(h);
        }
    }

    if (is_last) {
        const float logit = bdp[0] + h * Wd[m] + hA * Wd[mn] + hB * Wd[mp];
        if (k == 0) out[g >> 2] = sigm_n(logit);
    } else {
        hbuf[g] = h; cbuf[g] = c;
    }
}

extern "C" void kernel_launch(void* const* d_in, const int* in_sizes, int n_in,
                              void* d_out, int out_size, void* d_ws, size_t ws_size,
                              hipStream_t stream) {
    (void)in_sizes; (void)n_in; (void)out_size;
    const float* x  = (const float*)d_in[0];
    const float* W  = (const float*)d_in[1];
    const float* U  = (const float*)d_in[2];
    const float* b  = (const float*)d_in[3];
    const float* Wd = (const float*)d_in[4];
    const float* bd = (const float*)d_in[5];
    float* out = (float*)d_out;

    const size_t need_fused = (size_t)T_SZ * B_SZ * NG * sizeof(float);   // 50.3 MB
    if (ws_size >= need_fused) {
        float* xwbuf = (float*)d_ws;
        void* kargs[] = { (void*)&x, (void*)&W, (void*)&U, (void*)&b,
                          (void*)&Wd, (void*)&bd, (void*)&out, (void*)&xwbuf };
        hipError_t e = hipLaunchCooperativeKernel(
            reinterpret_cast<const void*>(&fused_lstm),
            dim3(GBLK), dim3(128), kargs, 0u, stream);
        if (e == hipSuccess) return;
    }

    // ---------- fallback: round-2 two-kernel path ----------
    const size_t state_bytes = (size_t)B_SZ * 4 * 2 * sizeof(float);
    const size_t avail = (ws_size > state_bytes) ? (ws_size - state_bytes) : 0;
    long long Tc = (long long)(avail / ((size_t)B_SZ * NG * sizeof(float)));
    if (Tc > T_SZ) Tc = T_SZ;
    Tc &= ~15LL;
    if (Tc < 16) return;   // no viable path (shouldn't happen: ws is large)

    float* hbuf  = (float*)d_ws;
    float* cbuf  = hbuf + (size_t)B_SZ * 4;
    float* xwbuf = cbuf + (size_t)B_SZ * 4;

    for (int t0 = 0; t0 < T_SZ; t0 += (int)Tc) {
        const int len = (T_SZ - t0 < (int)Tc) ? (T_SZ - t0) : (int)Tc;
        dim3 grid(len / 16, B_SZ / 16);
        xw_phase<<<grid, 256, 0, stream>>>(x, W, b, xwbuf, t0);
        lstm_scan<<<(B_SZ * 4) / 64, 64, 0, stream>>>(xwbuf, U, Wd, bd, out, hbuf, cbuf,
                                                      len, t0 == 0 ? 1 : 0,
                                                      (t0 + len >= T_SZ) ? 1 : 0);
    }
}

// Round 5
// 163.294 us; speedup vs baseline: 3.0987x; 3.0987x over previous
//
#include <hip/hip_runtime.h>
#include <cstdint>

#define B_SZ 2048
#define T_SZ 512
#define F_SZ 64
#define NG   12   // 4*H, H=3

// log2(e); gates pre-scaled by -L2E (sigmoid) / -2*L2E (tanh) in phase 1
#define L2E 1.4426950408889634f

__device__ __forceinline__ float fast_rcp(float x) { return __builtin_amdgcn_rcpf(x); }
__device__ __forceinline__ float exp2h(float x)    { return __builtin_amdgcn_exp2f(x); }
__device__ __forceinline__ float sigm_s(float zs)  { return fast_rcp(1.0f + exp2h(zs)); }
__device__ __forceinline__ float tanh_s(float zs)  { return fmaf(2.0f, fast_rcp(1.0f + exp2h(zs)), -1.0f); }
__device__ __forceinline__ float sigm_n(float x)   { return sigm_s(x * (-L2E)); }
__device__ __forceinline__ float tanh_n(float x)   { return tanh_s(x * (-2.0f * L2E)); }

template<int CTRL>
__device__ __forceinline__ float qperm(float v) {
    return __int_as_float(__builtin_amdgcn_mov_dpp(__float_as_int(v), CTRL, 0xF, 0xF, false));
}
#define QPA 9    // lane k <- src[{1,2,0,0}[k]]  -> h_{(m+1)%3}
#define QPB 82   // lane k <- src[{2,0,1,1}[k]]  -> h_{(m+2)%3}

// ---------------- phase 1 v2: LDS-staged, fully coalesced both sides ----------------
// block = 256 threads, tile = 16 b x 16 t. Each b-row of the tile is a 4 KB
// contiguous run of x -> staged with lane-consecutive float4 (perfect coalescing).
__global__ __launch_bounds__(256) void xw_phase(const float* __restrict__ x,
                                                const float* __restrict__ W,
                                                const float* __restrict__ bias,
                                                float* __restrict__ xw,
                                                int t0) {
    __shared__ float Ws[F_SZ * NG];
    __shared__ float bs[NG];
    __shared__ float xs[16 * 16 * 68];   // [b][t][68] (4-float pad)
    __shared__ float trs[16 * 196];      // [t][b*12] transpose buffer

    const int tid = threadIdx.x;

    // stage scaled/reordered weights (p = m*4+q  <-  W col q*3+m)
    for (int i = tid; i < F_SZ * NG; i += 256) {
        const int f = i / NG, p = i - f * NG;
        const int mm = p >> 2, q = p & 3;
        const float sc = (q == 2) ? (-2.0f * L2E) : (-L2E);
        Ws[i] = W[f * NG + q * 3 + mm] * sc;
    }
    if (tid < NG) {
        const int mm = tid >> 2, q = tid & 3;
        const float sc = (q == 2) ? (-2.0f * L2E) : (-L2E);
        bs[tid] = bias[q * 3 + mm] * sc;
    }

    const int tileT = blockIdx.x;        // within chunk
    const int tileB = blockIdx.y;
    const int tbase = t0 + tileT * 16;

    // ---- stage: 16 rows x 4 KB, each row one fully-coalesced pass of 256 lanes ----
    {
        const int tsub = tid >> 4;           // (tid*4)/64
        const int fo   = (tid & 15) * 4;     // (tid*4)%64
        const float* src0 = x + ((size_t)(tileB * 16) * T_SZ + tbase) * F_SZ + tid * 4;
        #pragma unroll
        for (int it = 0; it < 16; ++it) {
            const float4 v = *reinterpret_cast<const float4*>(src0 + (size_t)it * T_SZ * F_SZ);
            *reinterpret_cast<float4*>(&xs[(it * 16 + tsub) * 68 + fo]) = v;
        }
    }
    __syncthreads();

    // ---- compute: one (b,t) row per thread ----
    const int cb = tid >> 4, ct = tid & 15;
    float acc[NG];
    #pragma unroll
    for (int p = 0; p < NG; ++p) acc[p] = bs[p];
    {
        const float* row = &xs[(cb * 16 + ct) * 68];
        #pragma unroll
        for (int j = 0; j < 16; ++j) {
            const float4 xv = *reinterpret_cast<const float4*>(row + 4 * j);
            #pragma unroll
            for (int jj = 0; jj < 4; ++jj) {
                const float xsv = (jj == 0) ? xv.x : (jj == 1) ? xv.y : (jj == 2) ? xv.z : xv.w;
                const float* wr = &Ws[(j * 4 + jj) * NG];
                #pragma unroll
                for (int p = 0; p < NG; ++p) acc[p] = fmaf(xsv, wr[p], acc[p]);
            }
        }
    }

    // ---- transpose via LDS, then coalesced 768-B-run writes ----
    {
        float* tw = &trs[ct * 196 + cb * NG];
        *reinterpret_cast<float4*>(tw + 0) = make_float4(acc[0], acc[1], acc[2],  acc[3]);
        *reinterpret_cast<float4*>(tw + 4) = make_float4(acc[4], acc[5], acc[6],  acc[7]);
        *reinterpret_cast<float4*>(tw + 8) = make_float4(acc[8], acc[9], acc[10], acc[11]);
    }
    __syncthreads();
    {
        const int r = tid >> 4, part = tid & 15;
        const float* lp = &trs[r * 196 + part * NG];
        float* op = xw + ((size_t)(tileT * 16 + r) * B_SZ + tileB * 16 + part) * NG;
        *reinterpret_cast<float4*>(op + 0) = *reinterpret_cast<const float4*>(lp + 0);
        *reinterpret_cast<float4*>(op + 4) = *reinterpret_cast<const float4*>(lp + 4);
        *reinterpret_cast<float4*>(op + 8) = *reinterpret_cast<const float4*>(lp + 8);
    }
}

// ---------------- phase 2 v2: quad-per-element scan, 16-deep prefetch ----------------
__global__ __launch_bounds__(64) void lstm_scan(const float* __restrict__ xw,
                                                const float* __restrict__ U,
                                                const float* __restrict__ Wd,
                                                const float* __restrict__ bdp,
                                                float* __restrict__ out,
                                                float* __restrict__ hbuf,
                                                float* __restrict__ cbuf,
                                                int len, int is_first, int is_last) {
    const int g = blockIdx.x * 64 + threadIdx.x;
    const int k = g & 3;
    const int m  = (k < 3) ? k : 2;
    const int mn = (m + 1 == 3) ? 0 : m + 1;
    const int mp = (m + 2 >= 3) ? m - 1 : m + 2;

    float u_own[4], u_nxt[4], u_prv[4];
    #pragma unroll
    for (int q = 0; q < 4; ++q) {
        const float sc = (q == 2) ? (-2.0f * L2E) : (-L2E);
        const int col = q * 3 + m;
        u_own[q] = U[m  * NG + col] * sc;
        u_nxt[q] = U[mn * NG + col] * sc;
        u_prv[q] = U[mp * NG + col] * sc;
    }

    float h, c, hA, hB;
    if (is_first) {
        h = c = hA = hB = 0.0f;
    } else {
        h = hbuf[g]; c = cbuf[g];
        hA = qperm<QPA>(h); hB = qperm<QPB>(h);
    }

    const size_t stride = (size_t)B_SZ * NG;
    const float* base = xw + (size_t)(g >> 2) * NG + m * 4;

    auto comp = [&](const float4& z4) {
        // z = (xw + h*u_own) + (hA*u_nxt + hB*u_prv): short dep tree after h
        const float z0 = fmaf(h, u_own[0], z4.x) + fmaf(hA, u_nxt[0], hB * u_prv[0]);
        const float z1 = fmaf(h, u_own[1], z4.y) + fmaf(hA, u_nxt[1], hB * u_prv[1]);
        const float z2 = fmaf(h, u_own[2], z4.z) + fmaf(hA, u_nxt[2], hB * u_prv[2]);
        const float z3 = fmaf(h, u_own[3], z4.w) + fmaf(hA, u_nxt[3], hB * u_prv[3]);
        const float ai = sigm_s(z0);
        const float af = sigm_s(z1);
        const float ag = tanh_s(z2);
        const float ao = sigm_s(z3);
        c = fmaf(af, c, ai * ag);
        h = ao * tanh_n(c);
        hA = qperm<QPA>(h);
        hB = qperm<QPB>(h);
    };

    float4 pf[16];
    #pragma unroll
    for (int s = 0; s < 16; ++s)
        pf[s] = *reinterpret_cast<const float4*>(base + (size_t)s * stride);
    const float* pn = base + (size_t)16 * stride;

    int t = 0;
    for (; t + 16 < len; t += 16) {              // main loop: unconditional prefetch
        #pragma unroll
        for (int s = 0; s < 16; ++s) {
            const float4 z4 = pf[s];
            pf[s] = *reinterpret_cast<const float4*>(pn);
            pn += stride;
            comp(z4);
        }
    }
    #pragma unroll
    for (int s = 0; s < 16; ++s) comp(pf[s]);    // epilogue: drain

    if (is_last) {
        const float logit = bdp[0] + h * Wd[m] + hA * Wd[mn] + hB * Wd[mp];
        if (k == 0) out[g >> 2] = sigm_n(logit);
    } else {
        hbuf[g] = h; cbuf[g] = c;
    }
}

extern "C" void kernel_launch(void* const* d_in, const int* in_sizes, int n_in,
                              void* d_out, int out_size, void* d_ws, size_t ws_size,
                              hipStream_t stream) {
    (void)in_sizes; (void)n_in; (void)out_size;
    const float* x  = (const float*)d_in[0];
    const float* W  = (const float*)d_in[1];
    const float* U  = (const float*)d_in[2];
    const float* b  = (const float*)d_in[3];
    const float* Wd = (const float*)d_in[4];
    const float* bd = (const float*)d_in[5];
    float* out = (float*)d_out;

    const size_t state_bytes = (size_t)B_SZ * 4 * 2 * sizeof(float);
    const size_t avail = (ws_size > state_bytes) ? (ws_size - state_bytes) : 0;
    long long Tc = (long long)(avail / ((size_t)B_SZ * NG * sizeof(float)));
    if (Tc > T_SZ) Tc = T_SZ;
    Tc &= ~15LL;                     // tiles of 16 t; scan pipeline depth 16
    if (Tc < 16) return;             // ws is 1 GB in practice; never hit

    float* hbuf  = (float*)d_ws;
    float* cbuf  = hbuf + (size_t)B_SZ * 4;
    float* xwbuf = cbuf + (size_t)B_SZ * 4;

    for (int t0 = 0; t0 < T_SZ; t0 += (int)Tc) {
        const int len = (T_SZ - t0 < (int)Tc) ? (T_SZ - t0) : (int)Tc;   // %16==0
        dim3 grid(len / 16, B_SZ / 16);
        xw_phase<<<grid, 256, 0, stream>>>(x, W, b, xwbuf, t0);
        lstm_scan<<<(B_SZ * 4) / 64, 64, 0, stream>>>(xwbuf, U, Wd, bd, out, hbuf, cbuf,
                                                      len, t0 == 0 ? 1 : 0,
                                                      (t0 + len >= T_SZ) ? 1 : 0);
    }
}